// Round 7
// baseline (458.317 us; speedup 1.0000x reference)
//
#include <hip/hip_runtime.h>
#include <cstdint>

// ---------------------------------------------------------------------------
// SelfAttentionBlock: LN1 -> QKV -> MHA -> proj(+res) -> LN2 -> FFN(+res)
// B=8 N=2048 D=384 H=6 DK=64.  bf16 MFMA for all matmuls, fp32 LN/softmax/
// GELU/residuals.  Verified MFMA layouts (16x16x32 / shape family):
//   A[m=lane&15][k=(lane>>4)*8+j]  B[k=(lane>>4)*8+j][n=lane&15]
//   C/D[row=(lane>>4)*4+r][col=lane&15]
// 16x16x16 (_1k): A[m=lane&15][k=(lane>>4)*4+i], C/D same shape family.
// Round 7: attention with ZERO LDS. R6 post-mortem showed attn is LDS-pipe +
// VALU throughput-bound (pipe busy-times invariant across occupancy changes;
// conflicts ~31us/CU at R6). K b-frags (b128) and V b-frags (b64, from the
// pre-transposed vt) are loaded directly from global: per-head K/V (512KB) is
// L2-resident, each vt 128B line is fully consumed within one j-tile, and the
// L2 path is idle (HBM 13%). No staging, no barriers, no bank conflicts.
// ---------------------------------------------------------------------------

typedef __bf16 bf16;
typedef __bf16 bf16x8 __attribute__((ext_vector_type(8)));
typedef __bf16 bf16x4 __attribute__((ext_vector_type(4)));
typedef short s16x4 __attribute__((ext_vector_type(4)));
typedef float floatx4 __attribute__((ext_vector_type(4)));
typedef uint32_t __attribute__((address_space(1))) gu32;
typedef uint32_t __attribute__((address_space(3))) lu32;

#define NN 2048
#define DD 384
#define HH 6
#define DK 64
#define BB 8
#define MM (BB * NN)   // 16384 rows
#define D3 (3 * DD)    // 1152
#define D2 (2 * DD)    // 768
#define CH (3 + DD)    // 387 output channels

// 0.125 * log2(e): folded into stored Q so softmax is p = exp2(q.k)
#define QSCALE 0.18033688011112042f

static __device__ __forceinline__ s16x4 as_s16x4(bf16x4 v) {
    union { bf16x4 b; s16x4 s; } u; u.b = v; return u.s;
}

// ---------------- small utility kernels ----------------

// all four weight casts in one launch
__global__ void cast_all_kernel(const float* __restrict__ w_qkv, const float* __restrict__ w_o,
                                const float* __restrict__ w1, const float* __restrict__ w2,
                                bf16* __restrict__ o_qkv, bf16* __restrict__ o_o,
                                bf16* __restrict__ o_w1, bf16* __restrict__ o_w2) {
    int i = blockIdx.x * 256 + threadIdx.x;   // total 1179648
    if (i < 442368) o_qkv[i] = (bf16)w_qkv[i];
    else if (i < 589824) o_o[i - 442368] = (bf16)w_o[i - 442368];
    else if (i < 884736) o_w1[i - 589824] = (bf16)w1[i - 589824];
    else o_w2[i - 884736] = (bf16)w2[i - 884736];
}

__global__ void coords_kernel(const float* __restrict__ pts, float* __restrict__ out) {
    int i = blockIdx.x * 256 + threadIdx.x;            // 8*3*2048 = 49152 total
    int b = i / (3 * NN), r = i % (3 * NN);
    out[(size_t)b * CH * NN + r] = pts[(size_t)b * CH * NN + r];
}

// points (B, 3+D, N) -> feats (B, N, D), fp32
__global__ void transpose_kernel(const float* __restrict__ pts, float* __restrict__ feats) {
    __shared__ float T[32][33];
    int n0 = blockIdx.x * 32, d0 = blockIdx.y * 32, b = blockIdx.z;
    int tx = threadIdx.x, ty = threadIdx.y;
    const float* src = pts + (size_t)b * CH * NN;
#pragma unroll
    for (int i = 0; i < 4; ++i)
        T[ty + i * 8][tx] = src[(size_t)(3 + d0 + ty + i * 8) * NN + n0 + tx];
    __syncthreads();
    float* dst = feats + (size_t)b * NN * DD;
#pragma unroll
    for (int i = 0; i < 4; ++i)
        dst[(size_t)(n0 + ty + i * 8) * DD + d0 + tx] = T[tx][ty + i * 8];
}

// rows of 384, one wave per row, fp32 in -> bf16 out
__global__ __launch_bounds__(256) void ln_kernel(const float* __restrict__ x,
                                                 const float* __restrict__ g,
                                                 const float* __restrict__ bta,
                                                 bf16* __restrict__ out) {
    int wave = threadIdx.x >> 6, lane = threadIdx.x & 63;
    int row = blockIdx.x * 4 + wave;
    const float* xr = x + (size_t)row * DD;
    float v[6], s = 0.f, sq = 0.f;
#pragma unroll
    for (int i = 0; i < 6; ++i) { v[i] = xr[lane + i * 64]; s += v[i]; sq += v[i] * v[i]; }
#pragma unroll
    for (int o = 1; o < 64; o <<= 1) { s += __shfl_xor(s, o); sq += __shfl_xor(sq, o); }
    float mu = s * (1.f / DD);
    float var = sq * (1.f / DD) - mu * mu;
    float rs = rsqrtf(var + 1e-5f);
    bf16* orow = out + (size_t)row * DD;
#pragma unroll
    for (int i = 0; i < 6; ++i) {
        int d = lane + i * 64;
        orow[d] = (bf16)((v[i] - mu) * rs * g[d] + bta[d]);
    }
}

// ---------------- GEMM: C[M,NC] = A[M,K] * W[NC,K]^T, fused epilogues ----------------
// Tile: 128 rows x TN cols.  TN=128: 4 waves 2x2 of 64x64 (MI=4).
//                            TN=64 : 4 waves stacked, 32x64 each (MI=2).
// MODE 0: QKV  -> bf16 qkv (Q cols pre-scaled by QSCALE), V transposed to vt
// MODE 1: proj -> fp32 x = C + bias + res
// MODE 2: FF1  -> bf16 gelu(C + bias)
// MODE 3: FF2  -> fp32 out[(b,3+c,n)] = C + bias + res   (final transposed store)
template <int NC, int K, int MODE, int TN>
__global__ __launch_bounds__(256, 2)
void gemm_bt(const bf16* __restrict__ A, const bf16* __restrict__ W,
             const float* __restrict__ bias, const float* __restrict__ res,
             bf16* __restrict__ obf, float* __restrict__ of32, bf16* __restrict__ vt) {
    constexpr int MI = (TN == 128) ? 4 : 2;
    __shared__ bf16 As[128 * 32];
    __shared__ bf16 Ws[TN * 32];
    const int t = threadIdx.x;
    const int wave = t >> 6, lane = t & 63;
    const int m0 = blockIdx.x * 128, n0 = blockIdx.y * TN;
    const int wm = (TN == 128) ? (wave >> 1) * 64 : wave * 32;
    const int wn = (TN == 128) ? (wave & 1) * 64 : 0;
    const int lr = lane & 15, quad = lane >> 4;
    const int sr = t >> 2, sc = (t & 3) * 8;

    floatx4 acc[MI][4];
#pragma unroll
    for (int mi = 0; mi < MI; ++mi)
#pragma unroll
        for (int ni = 0; ni < 4; ++ni) {
            floatx4 z = {0.f, 0.f, 0.f, 0.f};
            acc[mi][ni] = z;
        }

    for (int k0 = 0; k0 < K; k0 += 32) {
        __syncthreads();
        // async global->LDS staging, 16B/lane; LDS offset == 16*t (lane*16-contiguous)
#pragma unroll
        for (int i = 0; i < 2; ++i) {
            const int r = i * 64 + sr;
            __builtin_amdgcn_global_load_lds(
                (const gu32*)&A[(size_t)(m0 + r) * K + k0 + sc],
                (lu32*)&As[r * 32 + sc], 16, 0, 0);
        }
#pragma unroll
        for (int i = 0; i < TN / 64; ++i) {
            const int r = i * 64 + sr;
            __builtin_amdgcn_global_load_lds(
                (const gu32*)&W[(size_t)(n0 + r) * K + k0 + sc],
                (lu32*)&Ws[r * 32 + sc], 16, 0, 0);
        }
        __syncthreads();
        bf16x8 af[MI], bfr[4];
#pragma unroll
        for (int mi = 0; mi < MI; ++mi)
            af[mi] = *(const bf16x8*)&As[(wm + mi * 16 + lr) * 32 + quad * 8];
#pragma unroll
        for (int ni = 0; ni < 4; ++ni)
            bfr[ni] = *(const bf16x8*)&Ws[(wn + ni * 16 + lr) * 32 + quad * 8];
#pragma unroll
        for (int mi = 0; mi < MI; ++mi)
#pragma unroll
            for (int ni = 0; ni < 4; ++ni)
                acc[mi][ni] = __builtin_amdgcn_mfma_f32_16x16x32_bf16(af[mi], bfr[ni], acc[mi][ni], 0, 0, 0);
    }

#pragma unroll
    for (int mi = 0; mi < MI; ++mi) {
#pragma unroll
        for (int ni = 0; ni < 4; ++ni) {
            const int r0 = m0 + wm + mi * 16 + quad * 4;  // 4 consecutive rows r0..r0+3
            const int c = n0 + wn + ni * 16 + lr;
            floatx4 v = acc[mi][ni];
            if constexpr (MODE == 0) {
                const int cb = n0 + wn + ni * 16;  // wave-uniform tile col base
                if (cb >= 2 * DD) {
                    // V: store transposed vt[b][h][dk][n], 4 consecutive n -> 8B store
                    const int hh = (c - 2 * DD) >> 6, dk = (c - 2 * DD) & 63;
                    const int b = r0 >> 11, n = r0 & (NN - 1);
                    bf16x4 pk;
#pragma unroll
                    for (int r = 0; r < 4; ++r) pk[r] = (bf16)v[r];
                    *(bf16x4*)&vt[((size_t)(b * HH + hh) * DK + dk) * NN + n] = pk;
                } else {
                    // Q columns (cb < DD) carry the softmax scale; K unscaled.
                    const float sc_q = (cb < DD) ? QSCALE : 1.0f;
#pragma unroll
                    for (int r = 0; r < 4; ++r) obf[(size_t)(r0 + r) * NC + c] = (bf16)(v[r] * sc_q);
                }
            } else if constexpr (MODE == 1) {
#pragma unroll
                for (int r = 0; r < 4; ++r)
                    of32[(size_t)(r0 + r) * NC + c] = v[r] + bias[c] + res[(size_t)(r0 + r) * NC + c];
            } else if constexpr (MODE == 2) {
#pragma unroll
                for (int r = 0; r < 4; ++r) {
                    float u = v[r] + bias[c];
                    obf[(size_t)(r0 + r) * NC + c] = (bf16)(0.5f * u * (1.f + erff(u * 0.70710678118f)));
                }
            } else {  // MODE 3: final residual + transposed store into output
                const int b = r0 >> 11, n = r0 & (NN - 1);
                float o4[4];
#pragma unroll
                for (int r = 0; r < 4; ++r)
                    o4[r] = v[r] + bias[c] + res[(size_t)(r0 + r) * DD + c];
                float4 val = make_float4(o4[0], o4[1], o4[2], o4[3]);
                *(float4*)&of32[((size_t)b * CH + 3 + c) * NN + n] = val;
            }
        }
    }
}

// ---------------- flash attention (round 7: zero LDS, zero barriers) ----------
// grid (N/128, B*H), 256 threads = 4 waves; wave owns 32 Q rows (frags in
// registers); K/V j-tiles of 64 read DIRECTLY from global (L2-resident);
// no-max streaming softmax via S^T; P in registers (16x16x16 PV).
__global__ __launch_bounds__(256, 3)
void attn_kernel(const bf16* __restrict__ qkv, const bf16* __restrict__ vt,
                 bf16* __restrict__ ctx) {
    const int t = threadIdx.x, wave = t >> 6, lane = t & 63;
    const int lr = lane & 15, quad = lane >> 4;
    const int bh = blockIdx.y, b = bh / HH, h = bh % HH;
    const int q0 = blockIdx.x * 128 + wave * 32;       // this wave's 32 Q rows
    const bf16* qbase = qkv + (size_t)b * NN * D3 + h * DK;          // Q cols (pre-scaled)
    const bf16* kbase = qbase + DD;                                   // K cols
    const bf16* vbase = vt + (size_t)bh * DK * NN;

    // Q frags: wave-private, j-invariant -> registers (used as B-operand)
    bf16x8 aq[2][2];
#pragma unroll
    for (int mi = 0; mi < 2; ++mi)
#pragma unroll
        for (int ks = 0; ks < 2; ++ks)
            aq[mi][ks] = *(const bf16x8*)&qbase[(size_t)(q0 + mi * 16 + lr) * D3 +
                                                ks * 32 + quad * 8];

    // ones B-fragment (K=16) for the denominator MFMA
    bf16x4 ones4;
#pragma unroll
    for (int i = 0; i < 4; ++i) ones4[i] = (bf16)1.0f;
    const s16x4 ones_s = as_s16x4(ones4);

    floatx4 o[2][4], ol[2];
#pragma unroll
    for (int mi = 0; mi < 2; ++mi) {
        floatx4 z = {0.f, 0.f, 0.f, 0.f};
        ol[mi] = z;
#pragma unroll
        for (int nd = 0; nd < 4; ++nd) o[mi][nd] = z;
    }

    for (int j0 = 0; j0 < NN; j0 += 64) {
        // K fragments straight from global: lane reads 16B of row j0+nj*16+lr.
        bf16x8 bk[2][4];
#pragma unroll
        for (int ks = 0; ks < 2; ++ks)
#pragma unroll
            for (int nj = 0; nj < 4; ++nj)
                bk[ks][nj] = *(const bf16x8*)&kbase[(size_t)(j0 + nj * 16 + lr) * D3 +
                                                    ks * 32 + quad * 8];
        // V fragments straight from global vt[d][j]: 8B of row d=nd*16+lr.
        s16x4 bv[4][4];
#pragma unroll
        for (int nd = 0; nd < 4; ++nd)
#pragma unroll
            for (int nj = 0; nj < 4; ++nj)
                bv[nd][nj] = as_s16x4(*(const bf16x4*)&vbase[(size_t)(nd * 16 + lr) * NN +
                                                             j0 + nj * 16 + quad * 4]);

        // S^T = K * Q^T (operand swap).  C-layout: lane holds
        // j = nj*16+quad*4+{0..3}, q = mi*16+lr.
        floatx4 s[2][4];
#pragma unroll
        for (int mi = 0; mi < 2; ++mi)
#pragma unroll
            for (int nj = 0; nj < 4; ++nj) {
                floatx4 z = {0.f, 0.f, 0.f, 0.f};
                s[mi][nj] = z;
            }
#pragma unroll
        for (int ks = 0; ks < 2; ++ks)
#pragma unroll
            for (int nj = 0; nj < 4; ++nj)
#pragma unroll
                for (int mi = 0; mi < 2; ++mi)
                    s[mi][nj] = __builtin_amdgcn_mfma_f32_16x16x32_bf16(bk[ks][nj], aq[mi][ks],
                                                                        s[mi][nj], 0, 0, 0);

        // p = exp2(s) (scale folded into Q; bounded scores, shift-invariant).
        // Lane's (q=mi*16+lr, j=nj*16+quad*4+r) values are EXACTLY the
        // 16x16x16 A-fragment A[m=lr][k=quad*4+r] for PV step nj -> no LDS.
#pragma unroll
        for (int nj = 0; nj < 4; ++nj) {
            s16x4 ap[2];
#pragma unroll
            for (int mi = 0; mi < 2; ++mi) {
                bf16x4 pk;
#pragma unroll
                for (int r = 0; r < 4; ++r) pk[r] = (bf16)exp2f(s[mi][nj][r]);
                ap[mi] = as_s16x4(pk);
            }
            // O += P V (K=16 slice) ; l += P * ones
#pragma unroll
            for (int nd = 0; nd < 4; ++nd)
#pragma unroll
                for (int mi = 0; mi < 2; ++mi)
                    o[mi][nd] = __builtin_amdgcn_mfma_f32_16x16x16bf16_1k(ap[mi], bv[nd][nj],
                                                                          o[mi][nd], 0, 0, 0);
#pragma unroll
            for (int mi = 0; mi < 2; ++mi)
                ol[mi] = __builtin_amdgcn_mfma_f32_16x16x16bf16_1k(ap[mi], ones_s, ol[mi], 0, 0, 0);
        }
    }

    // finalize: ctx[b,n, h*64+d] = o/l  (bf16); l rows match o rows.
#pragma unroll
    for (int mi = 0; mi < 2; ++mi)
#pragma unroll
        for (int r = 0; r < 4; ++r) {
            const int n = q0 + mi * 16 + quad * 4 + r;
            const float inv = 1.0f / ol[mi][r];
#pragma unroll
            for (int nd = 0; nd < 4; ++nd) {
                const int d = h * DK + nd * 16 + lr;
                ctx[(size_t)(b * NN + n) * DD + d] = (bf16)(o[mi][nd][r] * inv);
            }
        }
}

// ---------------- host launch ----------------

extern "C" void kernel_launch(void* const* d_in, const int* in_sizes, int n_in,
                              void* d_out, int out_size, void* d_ws, size_t ws_size,
                              hipStream_t stream) {
    const float* points = (const float*)d_in[0];
    const float* ln1_g = (const float*)d_in[1];
    const float* ln1_b = (const float*)d_in[2];
    const float* w_qkv = (const float*)d_in[3];
    const float* w_o   = (const float*)d_in[4];
    const float* b_o   = (const float*)d_in[5];
    const float* ln2_g = (const float*)d_in[6];
    const float* ln2_b = (const float*)d_in[7];
    const float* w1    = (const float*)d_in[8];
    const float* b1    = (const float*)d_in[9];
    const float* w2    = (const float*)d_in[10];
    const float* b2    = (const float*)d_in[11];
    float* out = (float*)d_out;

    char* ws = (char*)d_ws;
    size_t off = 0;
    auto alloc = [&](size_t bytes) -> void* {
        void* p = ws + off;
        off += (bytes + 255) & ~(size_t)255;
        return p;
    };
    float* feats = (float*)alloc((size_t)MM * DD * 4);
    float* xbuf  = (float*)alloc((size_t)MM * DD * 4);
    bf16* h1     = (bf16*)alloc((size_t)MM * DD * 2);
    bf16* h2     = (bf16*)alloc((size_t)MM * DD * 2);
    bf16* qkvb   = (bf16*)alloc((size_t)MM * D3 * 2);
    bf16* vtb    = (bf16*)alloc((size_t)BB * HH * DK * NN * 2);
    bf16* ctx    = (bf16*)alloc((size_t)MM * DD * 2);
    bf16* ffh    = (bf16*)alloc((size_t)MM * D2 * 2);
    bf16* wqkv_bf = (bf16*)alloc((size_t)D3 * DD * 2);
    bf16* wo_bf   = (bf16*)alloc((size_t)DD * DD * 2);
    bf16* w1_bf   = (bf16*)alloc((size_t)D2 * DD * 2);
    bf16* w2_bf   = (bf16*)alloc((size_t)DD * D2 * 2);

    cast_all_kernel<<<1179648 / 256, 256, 0, stream>>>(w_qkv, w_o, w1, w2,
                                                       wqkv_bf, wo_bf, w1_bf, w2_bf);
    coords_kernel<<<(BB * 3 * NN) / 256, 256, 0, stream>>>(points, out);
    transpose_kernel<<<dim3(NN / 32, DD / 32, BB), dim3(32, 8), 0, stream>>>(points, feats);
    ln_kernel<<<MM / 4, 256, 0, stream>>>(feats, ln1_g, ln1_b, h1);
    gemm_bt<D3, DD, 0, 128><<<dim3(MM / 128, D3 / 128), 256, 0, stream>>>(
        h1, wqkv_bf, nullptr, nullptr, qkvb, nullptr, vtb);
    attn_kernel<<<dim3(NN / 128, BB * HH), 256, 0, stream>>>(qkvb, vtb, ctx);
    gemm_bt<DD, DD, 1, 64><<<dim3(MM / 128, DD / 64), 256, 0, stream>>>(
        ctx, wo_bf, b_o, feats, nullptr, xbuf, nullptr);
    ln_kernel<<<MM / 4, 256, 0, stream>>>(xbuf, ln2_g, ln2_b, h2);
    gemm_bt<D2, DD, 2, 128><<<dim3(MM / 128, D2 / 128), 256, 0, stream>>>(
        h2, w1_bf, b1, nullptr, ffh, nullptr, nullptr);
    gemm_bt<DD, D2, 3, 64><<<dim3(MM / 128, DD / 64), 256, 0, stream>>>(
        ffh, w2_bf, b2, xbuf, nullptr, out, nullptr);
}

// Round 8
// 289.779 us; speedup vs baseline: 1.5816x; 1.5816x over previous
//
#include <hip/hip_runtime.h>
#include <cstdint>

// ---------------------------------------------------------------------------
// SelfAttentionBlock: LN1 -> QKV -> MHA -> proj(+res) -> LN2 -> FFN(+res)
// B=8 N=2048 D=384 H=6 DK=64.  bf16 MFMA for all matmuls, fp32 LN/softmax/
// GELU/residuals.  Verified MFMA layouts (16x16x32 / shape family):
//   A[m=lane&15][k=(lane>>4)*8+j]  B[k=(lane>>4)*8+j][n=lane&15]
//   C/D[row=(lane>>4)*4+r][col=lane&15]
// 16x16x16 (_1k): A[m=lane&15][k=(lane>>4)*4+i], C/D same shape family.
// Round 8: REVERT R7 (direct-global frags = scatter reads, TA/TCP-bound,
// 2.6x regression).  Back to R5 attention (best: 103.5us) + one delta:
// j-tile 64 -> 128 (same bytes/conflict-benign strides, HALF the barriers).
// GEMMs unchanged from R6 (TN=64 proj/FF2, BK=32, global_load_lds).
// ---------------------------------------------------------------------------

typedef __bf16 bf16;
typedef __bf16 bf16x8 __attribute__((ext_vector_type(8)));
typedef __bf16 bf16x4 __attribute__((ext_vector_type(4)));
typedef short s16x4 __attribute__((ext_vector_type(4)));
typedef float floatx4 __attribute__((ext_vector_type(4)));
typedef uint32_t __attribute__((address_space(1))) gu32;
typedef uint32_t __attribute__((address_space(3))) lu32;

#define NN 2048
#define DD 384
#define HH 6
#define DK 64
#define BB 8
#define MM (BB * NN)   // 16384 rows
#define D3 (3 * DD)    // 1152
#define D2 (2 * DD)    // 768
#define CH (3 + DD)    // 387 output channels
#define LP 72          // K-tile LDS row stride: 36 dwords -> 4-bank rotation/row
#define LPV 136        // V-tile LDS row stride: 68 dwords -> 4-bank rotation/row

// 0.125 * log2(e): folded into stored Q so softmax is p = exp2(q.k)
#define QSCALE 0.18033688011112042f

static __device__ __forceinline__ s16x4 as_s16x4(bf16x4 v) {
    union { bf16x4 b; s16x4 s; } u; u.b = v; return u.s;
}

// ---------------- small utility kernels ----------------

// all four weight casts in one launch
__global__ void cast_all_kernel(const float* __restrict__ w_qkv, const float* __restrict__ w_o,
                                const float* __restrict__ w1, const float* __restrict__ w2,
                                bf16* __restrict__ o_qkv, bf16* __restrict__ o_o,
                                bf16* __restrict__ o_w1, bf16* __restrict__ o_w2) {
    int i = blockIdx.x * 256 + threadIdx.x;   // total 1179648
    if (i < 442368) o_qkv[i] = (bf16)w_qkv[i];
    else if (i < 589824) o_o[i - 442368] = (bf16)w_o[i - 442368];
    else if (i < 884736) o_w1[i - 589824] = (bf16)w1[i - 589824];
    else o_w2[i - 884736] = (bf16)w2[i - 884736];
}

__global__ void coords_kernel(const float* __restrict__ pts, float* __restrict__ out) {
    int i = blockIdx.x * 256 + threadIdx.x;            // 8*3*2048 = 49152 total
    int b = i / (3 * NN), r = i % (3 * NN);
    out[(size_t)b * CH * NN + r] = pts[(size_t)b * CH * NN + r];
}

// points (B, 3+D, N) -> feats (B, N, D), fp32
__global__ void transpose_kernel(const float* __restrict__ pts, float* __restrict__ feats) {
    __shared__ float T[32][33];
    int n0 = blockIdx.x * 32, d0 = blockIdx.y * 32, b = blockIdx.z;
    int tx = threadIdx.x, ty = threadIdx.y;
    const float* src = pts + (size_t)b * CH * NN;
#pragma unroll
    for (int i = 0; i < 4; ++i)
        T[ty + i * 8][tx] = src[(size_t)(3 + d0 + ty + i * 8) * NN + n0 + tx];
    __syncthreads();
    float* dst = feats + (size_t)b * NN * DD;
#pragma unroll
    for (int i = 0; i < 4; ++i)
        dst[(size_t)(n0 + ty + i * 8) * DD + d0 + tx] = T[tx][ty + i * 8];
}

// rows of 384, one wave per row, fp32 in -> bf16 out
__global__ __launch_bounds__(256) void ln_kernel(const float* __restrict__ x,
                                                 const float* __restrict__ g,
                                                 const float* __restrict__ bta,
                                                 bf16* __restrict__ out) {
    int wave = threadIdx.x >> 6, lane = threadIdx.x & 63;
    int row = blockIdx.x * 4 + wave;
    const float* xr = x + (size_t)row * DD;
    float v[6], s = 0.f, sq = 0.f;
#pragma unroll
    for (int i = 0; i < 6; ++i) { v[i] = xr[lane + i * 64]; s += v[i]; sq += v[i] * v[i]; }
#pragma unroll
    for (int o = 1; o < 64; o <<= 1) { s += __shfl_xor(s, o); sq += __shfl_xor(sq, o); }
    float mu = s * (1.f / DD);
    float var = sq * (1.f / DD) - mu * mu;
    float rs = rsqrtf(var + 1e-5f);
    bf16* orow = out + (size_t)row * DD;
#pragma unroll
    for (int i = 0; i < 6; ++i) {
        int d = lane + i * 64;
        orow[d] = (bf16)((v[i] - mu) * rs * g[d] + bta[d]);
    }
}

// ---------------- GEMM: C[M,NC] = A[M,K] * W[NC,K]^T, fused epilogues ----------------
// Tile: 128 rows x TN cols.  TN=128: 4 waves 2x2 of 64x64 (MI=4).
//                            TN=64 : 4 waves stacked, 32x64 each (MI=2).
// MODE 0: QKV  -> bf16 qkv (Q cols pre-scaled by QSCALE), V transposed to vt
// MODE 1: proj -> fp32 x = C + bias + res
// MODE 2: FF1  -> bf16 gelu(C + bias)
// MODE 3: FF2  -> fp32 out[(b,3+c,n)] = C + bias + res   (final transposed store)
template <int NC, int K, int MODE, int TN>
__global__ __launch_bounds__(256, 2)
void gemm_bt(const bf16* __restrict__ A, const bf16* __restrict__ W,
             const float* __restrict__ bias, const float* __restrict__ res,
             bf16* __restrict__ obf, float* __restrict__ of32, bf16* __restrict__ vt) {
    constexpr int MI = (TN == 128) ? 4 : 2;
    __shared__ bf16 As[128 * 32];
    __shared__ bf16 Ws[TN * 32];
    const int t = threadIdx.x;
    const int wave = t >> 6, lane = t & 63;
    const int m0 = blockIdx.x * 128, n0 = blockIdx.y * TN;
    const int wm = (TN == 128) ? (wave >> 1) * 64 : wave * 32;
    const int wn = (TN == 128) ? (wave & 1) * 64 : 0;
    const int lr = lane & 15, quad = lane >> 4;
    const int sr = t >> 2, sc = (t & 3) * 8;

    floatx4 acc[MI][4];
#pragma unroll
    for (int mi = 0; mi < MI; ++mi)
#pragma unroll
        for (int ni = 0; ni < 4; ++ni) {
            floatx4 z = {0.f, 0.f, 0.f, 0.f};
            acc[mi][ni] = z;
        }

    for (int k0 = 0; k0 < K; k0 += 32) {
        __syncthreads();
        // async global->LDS staging, 16B/lane; LDS offset == 16*t (lane*16-contiguous)
#pragma unroll
        for (int i = 0; i < 2; ++i) {
            const int r = i * 64 + sr;
            __builtin_amdgcn_global_load_lds(
                (const gu32*)&A[(size_t)(m0 + r) * K + k0 + sc],
                (lu32*)&As[r * 32 + sc], 16, 0, 0);
        }
#pragma unroll
        for (int i = 0; i < TN / 64; ++i) {
            const int r = i * 64 + sr;
            __builtin_amdgcn_global_load_lds(
                (const gu32*)&W[(size_t)(n0 + r) * K + k0 + sc],
                (lu32*)&Ws[r * 32 + sc], 16, 0, 0);
        }
        __syncthreads();
        bf16x8 af[MI], bfr[4];
#pragma unroll
        for (int mi = 0; mi < MI; ++mi)
            af[mi] = *(const bf16x8*)&As[(wm + mi * 16 + lr) * 32 + quad * 8];
#pragma unroll
        for (int ni = 0; ni < 4; ++ni)
            bfr[ni] = *(const bf16x8*)&Ws[(wn + ni * 16 + lr) * 32 + quad * 8];
#pragma unroll
        for (int mi = 0; mi < MI; ++mi)
#pragma unroll
            for (int ni = 0; ni < 4; ++ni)
                acc[mi][ni] = __builtin_amdgcn_mfma_f32_16x16x32_bf16(af[mi], bfr[ni], acc[mi][ni], 0, 0, 0);
    }

#pragma unroll
    for (int mi = 0; mi < MI; ++mi) {
#pragma unroll
        for (int ni = 0; ni < 4; ++ni) {
            const int r0 = m0 + wm + mi * 16 + quad * 4;  // 4 consecutive rows r0..r0+3
            const int c = n0 + wn + ni * 16 + lr;
            floatx4 v = acc[mi][ni];
            if constexpr (MODE == 0) {
                const int cb = n0 + wn + ni * 16;  // wave-uniform tile col base
                if (cb >= 2 * DD) {
                    // V: store transposed vt[b][h][dk][n], 4 consecutive n -> 8B store
                    const int hh = (c - 2 * DD) >> 6, dk = (c - 2 * DD) & 63;
                    const int b = r0 >> 11, n = r0 & (NN - 1);
                    bf16x4 pk;
#pragma unroll
                    for (int r = 0; r < 4; ++r) pk[r] = (bf16)v[r];
                    *(bf16x4*)&vt[((size_t)(b * HH + hh) * DK + dk) * NN + n] = pk;
                } else {
                    // Q columns (cb < DD) carry the softmax scale; K unscaled.
                    const float sc_q = (cb < DD) ? QSCALE : 1.0f;
#pragma unroll
                    for (int r = 0; r < 4; ++r) obf[(size_t)(r0 + r) * NC + c] = (bf16)(v[r] * sc_q);
                }
            } else if constexpr (MODE == 1) {
#pragma unroll
                for (int r = 0; r < 4; ++r)
                    of32[(size_t)(r0 + r) * NC + c] = v[r] + bias[c] + res[(size_t)(r0 + r) * NC + c];
            } else if constexpr (MODE == 2) {
#pragma unroll
                for (int r = 0; r < 4; ++r) {
                    float u = v[r] + bias[c];
                    obf[(size_t)(r0 + r) * NC + c] = (bf16)(0.5f * u * (1.f + erff(u * 0.70710678118f)));
                }
            } else {  // MODE 3: final residual + transposed store into output
                const int b = r0 >> 11, n = r0 & (NN - 1);
                float o4[4];
#pragma unroll
                for (int r = 0; r < 4; ++r)
                    o4[r] = v[r] + bias[c] + res[(size_t)(r0 + r) * DD + c];
                float4 val = make_float4(o4[0], o4[1], o4[2], o4[3]);
                *(float4*)&of32[((size_t)b * CH + 3 + c) * NN + n] = val;
            }
        }
    }
}

// ---------------- flash attention (round 8 = R5 structure, j-tile 128) -------
// grid (N/128, B*H), 256 threads = 4 waves; wave owns 32 Q rows (frags in
// registers); K/V j-tiles of 128 (LDS-staged, padded strides); no-max
// streaming softmax via S^T; P in registers (16x16x16 PV).  2 barriers/tile,
// 16 tiles (half of R5's 32).
__global__ __launch_bounds__(256, 3)
void attn_kernel(const bf16* __restrict__ qkv, const bf16* __restrict__ vt,
                 bf16* __restrict__ ctx) {
    __shared__ bf16 Ks[128 * LP];       // K tile [j][d], j=0..127
    __shared__ bf16 Vs[64 * LPV];       // V^T tile [d][j], d=0..63, j=0..127
    const int t = threadIdx.x, wave = t >> 6, lane = t & 63;
    const int lr = lane & 15, quad = lane >> 4;
    const int bh = blockIdx.y, b = bh / HH, h = bh % HH;
    const int q0 = blockIdx.x * 128 + wave * 32;       // this wave's 32 Q rows
    const bf16* qbase = qkv + (size_t)b * NN * D3 + h * DK;          // Q cols (pre-scaled)
    const bf16* kbase = qbase + DD;                                   // K cols
    const bf16* vbase = vt + (size_t)bh * DK * NN;

    // Q frags: wave-private, j-invariant -> registers (used as B-operand)
    bf16x8 aq[2][2];
#pragma unroll
    for (int mi = 0; mi < 2; ++mi)
#pragma unroll
        for (int ks = 0; ks < 2; ++ks)
            aq[mi][ks] = *(const bf16x8*)&qbase[(size_t)(q0 + mi * 16 + lr) * D3 +
                                                ks * 32 + quad * 8];

    // ones B-fragment (K=16) for the denominator MFMA
    bf16x4 ones4;
#pragma unroll
    for (int i = 0; i < 4; ++i) ones4[i] = (bf16)1.0f;
    const s16x4 ones_s = as_s16x4(ones4);

    floatx4 o[2][4], ol[2];
#pragma unroll
    for (int mi = 0; mi < 2; ++mi) {
        floatx4 z = {0.f, 0.f, 0.f, 0.f};
        ol[mi] = z;
#pragma unroll
        for (int nd = 0; nd < 4; ++nd) o[mi][nd] = z;
    }

    for (int j0 = 0; j0 < NN; j0 += 128) {
        __syncthreads();
        {   // stage K tile: 128 rows x 64 cols (rows of 64 cols, 8 lanes/row)
            const int rr = t >> 3, cc = (t & 7) * 8;
#pragma unroll
            for (int i = 0; i < 4; ++i) {
                const int j = i * 32 + rr;
                *(bf16x8*)&Ks[j * LP + cc] =
                    *(const bf16x8*)&kbase[(size_t)(j0 + j) * D3 + cc];
            }
            // stage V^T tile: 64 rows (d) x 128 cols (j), 16 lanes/row
            const int rr2 = t >> 4, cc2 = (t & 15) * 8;
#pragma unroll
            for (int i = 0; i < 4; ++i) {
                const int d = i * 16 + rr2;
                *(bf16x8*)&Vs[d * LPV + cc2] =
                    *(const bf16x8*)&vbase[(size_t)d * NN + j0 + cc2];
            }
        }
        __syncthreads();

        // S^T = K * Q^T (operand swap).  C-layout: lane holds
        // j = nj*16+quad*4+{0..3}, q = mi*16+lr.
        floatx4 s[2][8];
#pragma unroll
        for (int mi = 0; mi < 2; ++mi)
#pragma unroll
            for (int nj = 0; nj < 8; ++nj) {
                floatx4 z = {0.f, 0.f, 0.f, 0.f};
                s[mi][nj] = z;
            }
#pragma unroll
        for (int ks = 0; ks < 2; ++ks)
#pragma unroll
            for (int nj = 0; nj < 8; ++nj) {
                bf16x8 bk = *(const bf16x8*)&Ks[(nj * 16 + lr) * LP + ks * 32 + quad * 8];
#pragma unroll
                for (int mi = 0; mi < 2; ++mi)
                    s[mi][nj] = __builtin_amdgcn_mfma_f32_16x16x32_bf16(bk, aq[mi][ks],
                                                                        s[mi][nj], 0, 0, 0);
            }

        // p = exp2(s) (scale folded into Q; bounded scores, shift-invariant).
        // Lane's (q=mi*16+lr, j=nj*16+quad*4+r) values are EXACTLY the
        // 16x16x16 A-fragment A[m=lr][k=quad*4+r] for PV step nj -> no LDS.
#pragma unroll
        for (int nj = 0; nj < 8; ++nj) {
            s16x4 ap[2];
#pragma unroll
            for (int mi = 0; mi < 2; ++mi) {
                bf16x4 pk;
#pragma unroll
                for (int r = 0; r < 4; ++r) pk[r] = (bf16)exp2f(s[mi][nj][r]);
                ap[mi] = as_s16x4(pk);
            }
            // O += P V (K=16 slice) ; l += P * ones
#pragma unroll
            for (int nd = 0; nd < 4; ++nd) {
                s16x4 bv = as_s16x4(*(const bf16x4*)&Vs[(nd * 16 + lr) * LPV +
                                                        nj * 16 + quad * 4]);
#pragma unroll
                for (int mi = 0; mi < 2; ++mi)
                    o[mi][nd] = __builtin_amdgcn_mfma_f32_16x16x16bf16_1k(ap[mi], bv,
                                                                          o[mi][nd], 0, 0, 0);
            }
#pragma unroll
            for (int mi = 0; mi < 2; ++mi)
                ol[mi] = __builtin_amdgcn_mfma_f32_16x16x16bf16_1k(ap[mi], ones_s, ol[mi], 0, 0, 0);
        }
    }

    // finalize: ctx[b,n, h*64+d] = o/l  (bf16); l rows match o rows.
#pragma unroll
    for (int mi = 0; mi < 2; ++mi)
#pragma unroll
        for (int r = 0; r < 4; ++r) {
            const int n = q0 + mi * 16 + quad * 4 + r;
            const float inv = 1.0f / ol[mi][r];
#pragma unroll
            for (int nd = 0; nd < 4; ++nd) {
                const int d = h * DK + nd * 16 + lr;
                ctx[(size_t)(b * NN + n) * DD + d] = (bf16)(o[mi][nd][r] * inv);
            }
        }
}

// ---------------- host launch ----------------

extern "C" void kernel_launch(void* const* d_in, const int* in_sizes, int n_in,
                              void* d_out, int out_size, void* d_ws, size_t ws_size,
                              hipStream_t stream) {
    const float* points = (const float*)d_in[0];
    const float* ln1_g = (const float*)d_in[1];
    const float* ln1_b = (const float*)d_in[2];
    const float* w_qkv = (const float*)d_in[3];
    const float* w_o   = (const float*)d_in[4];
    const float* b_o   = (const float*)d_in[5];
    const float* ln2_g = (const float*)d_in[6];
    const float* ln2_b = (const float*)d_in[7];
    const float* w1    = (const float*)d_in[8];
    const float* b1    = (const float*)d_in[9];
    const float* w2    = (const float*)d_in[10];
    const float* b2    = (const float*)d_in[11];
    float* out = (float*)d_out;

    char* ws = (char*)d_ws;
    size_t off = 0;
    auto alloc = [&](size_t bytes) -> void* {
        void* p = ws + off;
        off += (bytes + 255) & ~(size_t)255;
        return p;
    };
    float* feats = (float*)alloc((size_t)MM * DD * 4);
    float* xbuf  = (float*)alloc((size_t)MM * DD * 4);
    bf16* h1     = (bf16*)alloc((size_t)MM * DD * 2);
    bf16* h2     = (bf16*)alloc((size_t)MM * DD * 2);
    bf16* qkvb   = (bf16*)alloc((size_t)MM * D3 * 2);
    bf16* vtb    = (bf16*)alloc((size_t)BB * HH * DK * NN * 2);
    bf16* ctx    = (bf16*)alloc((size_t)MM * DD * 2);
    bf16* ffh    = (bf16*)alloc((size_t)MM * D2 * 2);
    bf16* wqkv_bf = (bf16*)alloc((size_t)D3 * DD * 2);
    bf16* wo_bf   = (bf16*)alloc((size_t)DD * DD * 2);
    bf16* w1_bf   = (bf16*)alloc((size_t)D2 * DD * 2);
    bf16* w2_bf   = (bf16*)alloc((size_t)DD * D2 * 2);

    cast_all_kernel<<<1179648 / 256, 256, 0, stream>>>(w_qkv, w_o, w1, w2,
                                                       wqkv_bf, wo_bf, w1_bf, w2_bf);
    coords_kernel<<<(BB * 3 * NN) / 256, 256, 0, stream>>>(points, out);
    transpose_kernel<<<dim3(NN / 32, DD / 32, BB), dim3(32, 8), 0, stream>>>(points, feats);
    ln_kernel<<<MM / 4, 256, 0, stream>>>(feats, ln1_g, ln1_b, h1);
    gemm_bt<D3, DD, 0, 128><<<dim3(MM / 128, D3 / 128), 256, 0, stream>>>(
        h1, wqkv_bf, nullptr, nullptr, qkvb, nullptr, vtb);
    attn_kernel<<<dim3(NN / 128, BB * HH), 256, 0, stream>>>(qkvb, vtb, ctx);
    gemm_bt<DD, DD, 1, 64><<<dim3(MM / 128, DD / 64), 256, 0, stream>>>(
        ctx, wo_bf, b_o, feats, nullptr, xbuf, nullptr);
    ln_kernel<<<MM / 4, 256, 0, stream>>>(xbuf, ln2_g, ln2_b, h2);
    gemm_bt<D2, DD, 2, 128><<<dim3(MM / 128, D2 / 128), 256, 0, stream>>>(
        h2, w1_bf, b1, nullptr, ffh, nullptr, nullptr);
    gemm_bt<DD, D2, 3, 64><<<dim3(MM / 128, DD / 64), 256, 0, stream>>>(
        ffh, w2_bf, b2, xbuf, nullptr, out, nullptr);
}